// Round 2
// 439.929 us; speedup vs baseline: 1.0229x; 1.0229x over previous
//
#include <hip/hip_runtime.h>
#include <math.h>

#define BB 64
#define TT 256
#define DEG 8
#define EE 128
#define NBUCKET 288
#define HID 100
#define H2 50

// ---------------- workspace layout (floats) ----------------
constexpr size_t OFF_STATS   = 0;        // 4: sum, sumsq, cnt, pad
constexpr size_t OFF_CDIST   = 4;        // 100
constexpr size_t OFF_CDIRX   = 104;      // 100
constexpr size_t OFF_CDIRY   = 204;      // 100
constexpr size_t OFF_BASE    = 304;      // 100
constexpr size_t OFF_V25     = 404;      // 25
constexpr size_t OFF_C25     = 429;      // 25
constexpr size_t OFF_OBZ     = 454;      // 1
constexpr size_t OFF_DESTPRE = 456;      // 64*100
constexpr size_t OFF_WF      = 6856;     // 128*100 (Wo @ om_W1[0:128])
constexpr size_t OFF_TT      = 32456;    // 16384*8 travel times
constexpr size_t OFF_Q       = 163528;   // 16384*128
constexpr size_t OFF_K       = OFF_Q + 16384 * 128;
constexpr size_t OFF_VP      = OFF_K + 16384 * 128;   // 16384*100

// ---------------- setup: prevec (blk 0) + destpre (1..64) + wfused (65..192) ----------------
__global__ void __launch_bounds__(256) k_setup(
    const int* destinations, const float* emb, const float* Wo,
    const float* dist_W, const float* dist_b, const float* dir_W, const float* dir_b,
    const float* tt_W, const float* tt_b, const float* ob_W1, const float* ob_b1,
    const float* ob_W2, const float* ob_b2, const float* om_W1, const float* om_b1,
    float* ws, float* out) {
    __shared__ float sh[EE];
    int blk = blockIdx.x;
    int j = threadIdx.x;
    if (blk == 0) {
        if (j < 4) ws[OFF_STATS + j] = 0.f;
        if (j == 0) out[0] = 0.f;
        if (j < HID) {
            float cd = 0.f, cx = 0.f, cy = 0.f, bs = om_b1[j];
            for (int f = 0; f < 50; f++) {
                float w1d = om_W1[(128 + f) * HID + j];
                float w1r = om_W1[(178 + f) * HID + j];
                cd += dist_W[f] * w1d;
                bs += dist_b[f] * w1d + dir_b[f] * w1r;
                cx += dir_W[f] * w1r;
                cy += dir_W[50 + f] * w1r;
            }
            ws[OFF_CDIST + j] = cd; ws[OFF_CDIRX + j] = cx;
            ws[OFF_CDIRY + j] = cy; ws[OFF_BASE + j] = bs;
        }
        if (j >= 128 && j < 153) {
            int jj = j - 128;
            float v = 0.f, c = ob_b1[jj];
            for (int i = 0; i < 50; i++) {
                v += tt_W[i] * ob_W1[i * 25 + jj];
                c += tt_b[i] * ob_W1[i * 25 + jj];
            }
            ws[OFF_V25 + jj] = v; ws[OFF_C25 + jj] = c;
        }
        if (j == 200) {
            float z = ob_b2[0];
            for (int i = 0; i < 25; i++) z += fmaxf(ob_b1[i], 0.f) * ob_W2[i];
            ws[OFF_OBZ] = z;
        }
    } else if (blk <= 64) {
        int b = blk - 1;
        if (j < EE) sh[j] = emb[(size_t)destinations[b] * EE + j];
        __syncthreads();
        if (j < HID) {
            float acc = 0.f;
            for (int i = 0; i < EE; i++) acc += sh[i] * om_W1[(228 + i) * HID + j];
            ws[OFF_DESTPRE + b * HID + j] = acc;
        }
    } else {
        int i = blk - 65;
        if (j < EE) sh[j] = Wo[i * EE + j];
        __syncthreads();
        if (j < HID) {
            float acc = 0.f;
            for (int jj = 0; jj < EE; jj++) acc += sh[jj] * om_W1[jj * HID + j];
            ws[OFF_WF + i * HID + j] = acc;
        }
    }
}

// ---------------- mid: QKV' GEMM (blocks 0..511) + whitening stats (512..767) ----------------
__global__ void __launch_bounds__(256) k_mid(
    const int* xs, const int* lengths, const int* adj, const int* seg,
    const int* stime, const float* tds, const float* emb,
    const float* Wq, const float* Wk, const float* Wv, float* ws) {
    __shared__ float smem[2 * 128 * 36 + 32];
    int blk = blockIdx.x;
    int tid = threadIdx.x;
    if (blk < 512) {
        float (*XT)[36]  = (float(*)[36])smem;
        float (*T1T)[36] = (float(*)[36])(smem + 128 * 36);
        int* vids = (int*)(smem + 2 * 128 * 36);
        int r0 = blk * 32;
        if (tid < 32) vids[tid] = xs[r0 + tid];
        __syncthreads();
        for (int c = 0; c < 16; c++) {
            int idx = c * 256 + tid;
            int r = idx >> 7, i = idx & 127;
            XT[i][r] = emb[(size_t)vids[r] * EE + i];
        }
        __syncthreads();
        int cg = tid & 31, rg = tid >> 5;
        const float* Wmats[2] = {Wq, Wk};
        float* Omats[2] = {ws + OFF_Q, ws + OFF_K};
        for (int mtx = 0; mtx < 2; mtx++) {
            const float* W = Wmats[mtx];
            float acc[4][4];
            #pragma unroll
            for (int a = 0; a < 4; a++)
                #pragma unroll
                for (int bb = 0; bb < 4; bb++) acc[a][bb] = 0.f;
            #pragma unroll 4
            for (int i = 0; i < EE; i++) {
                float4 av = *(const float4*)&XT[i][rg << 2];
                float4 wv = *(const float4*)&W[i * EE + (cg << 2)];
                acc[0][0] += av.x * wv.x; acc[0][1] += av.x * wv.y; acc[0][2] += av.x * wv.z; acc[0][3] += av.x * wv.w;
                acc[1][0] += av.y * wv.x; acc[1][1] += av.y * wv.y; acc[1][2] += av.y * wv.z; acc[1][3] += av.y * wv.w;
                acc[2][0] += av.z * wv.x; acc[2][1] += av.z * wv.y; acc[2][2] += av.z * wv.z; acc[2][3] += av.z * wv.w;
                acc[3][0] += av.w * wv.x; acc[3][1] += av.w * wv.y; acc[3][2] += av.w * wv.z; acc[3][3] += av.w * wv.w;
            }
            float* O = Omats[mtx];
            #pragma unroll
            for (int jj = 0; jj < 4; jj++)
                *(float4*)&O[(size_t)(r0 + (rg << 2) + jj) * EE + (cg << 2)] =
                    make_float4(acc[jj][0], acc[jj][1], acc[jj][2], acc[jj][3]);
        }
        // T1 = X @ Wv, transposed into LDS
        {
            float acc[4][4];
            #pragma unroll
            for (int a = 0; a < 4; a++)
                #pragma unroll
                for (int bb = 0; bb < 4; bb++) acc[a][bb] = 0.f;
            #pragma unroll 4
            for (int i = 0; i < EE; i++) {
                float4 av = *(const float4*)&XT[i][rg << 2];
                float4 wv = *(const float4*)&Wv[i * EE + (cg << 2)];
                acc[0][0] += av.x * wv.x; acc[0][1] += av.x * wv.y; acc[0][2] += av.x * wv.z; acc[0][3] += av.x * wv.w;
                acc[1][0] += av.y * wv.x; acc[1][1] += av.y * wv.y; acc[1][2] += av.y * wv.z; acc[1][3] += av.y * wv.w;
                acc[2][0] += av.z * wv.x; acc[2][1] += av.z * wv.y; acc[2][2] += av.z * wv.z; acc[2][3] += av.z * wv.w;
                acc[3][0] += av.w * wv.x; acc[3][1] += av.w * wv.y; acc[3][2] += av.w * wv.z; acc[3][3] += av.w * wv.w;
            }
            #pragma unroll
            for (int jj = 0; jj < 4; jj++)
                #pragma unroll
                for (int ii = 0; ii < 4; ii++)
                    T1T[(cg << 2) + ii][(rg << 2) + jj] = acc[jj][ii];
        }
        __syncthreads();
        if (cg < 25) {
            const float* WF = ws + OFF_WF;
            float acc[4][4];
            #pragma unroll
            for (int a = 0; a < 4; a++)
                #pragma unroll
                for (int bb = 0; bb < 4; bb++) acc[a][bb] = 0.f;
            #pragma unroll 4
            for (int i = 0; i < EE; i++) {
                float4 av = *(const float4*)&T1T[i][rg << 2];
                float4 wv = *(const float4*)&WF[i * HID + (cg << 2)];
                acc[0][0] += av.x * wv.x; acc[0][1] += av.x * wv.y; acc[0][2] += av.x * wv.z; acc[0][3] += av.x * wv.w;
                acc[1][0] += av.y * wv.x; acc[1][1] += av.y * wv.y; acc[1][2] += av.y * wv.z; acc[1][3] += av.y * wv.w;
                acc[2][0] += av.z * wv.x; acc[2][1] += av.z * wv.y; acc[2][2] += av.z * wv.z; acc[2][3] += av.z * wv.w;
                acc[3][0] += av.w * wv.x; acc[3][1] += av.w * wv.y; acc[3][2] += av.w * wv.z; acc[3][3] += av.w * wv.w;
            }
            float* VP = ws + OFF_VP;
            #pragma unroll
            for (int jj = 0; jj < 4; jj++)
                *(float4*)&VP[(size_t)(r0 + (rg << 2) + jj) * HID + (cg << 2)] =
                    make_float4(acc[jj][0], acc[jj][1], acc[jj][2], acc[jj][3]);
        }
    } else {
        // ---- stats ----
        float* rs = smem; float* rq = smem + 256; float* rc = smem + 512;
        int st = *stime;
        float lsum = 0.f, lsq = 0.f, lcnt = 0.f;
        int total = BB * TT * DEG;
        for (int idx = (blk - 512) * 256 + tid; idx < total; idx += 256 * 256) {
            int d = idx & 7;
            int bt = idx >> 3;
            int t = bt & 255;
            int b = bt >> 8;
            int len = lengths[b];
            if (t >= len - 1) continue;
            int v = xs[bt];
            int sg = seg[v * DEG + d];
            float tt = tds[(size_t)sg * NBUCKET + st];
            ws[OFF_TT + idx] = tt;
            int a = adj[v * DEG + d];
            if (a != 0) { lsum += tt; lsq += tt * tt; lcnt += 1.f; }
        }
        rs[tid] = lsum; rq[tid] = lsq; rc[tid] = lcnt;
        __syncthreads();
        for (int s = 128; s > 0; s >>= 1) {
            if (tid < s) { rs[tid] += rs[tid + s]; rq[tid] += rq[tid + s]; rc[tid] += rc[tid + s]; }
            __syncthreads();
        }
        if (tid == 0) {
            atomicAdd(&ws[OFF_STATS + 0], rs[0]);
            atomicAdd(&ws[OFF_STATS + 1], rq[0]);
            atomicAdd(&ws[OFF_STATS + 2], rc[0]);
        }
    }
}

// ---------------- fused attention + neighbor-MLP + CE: 8 queries/block ----------------
// LDS (floats, total 13160 = 51.4 KB -> 3 blocks/CU):
//   H1P[8][104]          @0      (832)   persists A->B
//   phase A union @832:
//     Qs[8][132]         @832    (1056)
//     S [8][260]         @1888   (2080)
//     Vs[64][104]        @3968   (6656)
//     pacc[128][8]       @10624  (1024)
//   phase B union @832:
//     W2s[100][56]       @832    (5600)
//     h1T[100][64]       @6432   (6400)
//   feats @12832: distR/uxR/uyR/obR[64] (256) | lgS[64] @13088 | nllS[8] @13152
__global__ void __launch_bounds__(256) k_attnfinal(
    const int* lengths, const int* xs, const int* xs_actions,
    const int* destinations, const int* adj, const float* locations,
    const float* om_W2, const float* om_b2, const float* om_W3, const float* om_b3,
    const float* ob_W2, const float* ob_b2,
    float* ws, float* out) {
    int blk = blockIdx.x;
    int tile = 31 - (blk >> 6);          // long tiles dispatch first
    int b = blk & 63;
    int t0 = tile << 3;
    int len = lengths[b];
    if (t0 >= len - 1) return;
    int nqv = len - 1 - t0; if (nqv > 8) nqv = 8;
    int nk = t0 + 8;
    __shared__ float smem[13160];
    float (*H1P)[104] = (float(*)[104])smem;
    float (*Qs)[132]  = (float(*)[132])(smem + 832);
    float (*S)[260]   = (float(*)[260])(smem + 1888);
    float (*Vs)[104]  = (float(*)[104])(smem + 3968);
    float (*pacc)[8]  = (float(*)[8])(smem + 10624);
    float (*W2s)[56]  = (float(*)[56])(smem + 832);
    float (*h1T)[64]  = (float(*)[64])(smem + 6432);
    float* distR = smem + 12832;
    float* uxR   = smem + 12896;
    float* uyR   = smem + 12960;
    float* obR   = smem + 13024;
    float* lgS   = smem + 13088;
    float* nllS  = smem + 13152;
    int tid = threadIdx.x;
    if (tid < 8) nllS[tid] = 0.f;
    // ---- stage Q (8 rows x 128) ----
    {
        const float* Qg = ws + OFF_Q + (size_t)(b * TT + t0) * EE;
        int r = tid >> 5, c4 = (tid & 31) << 2;
        *(float4*)&Qs[r][c4] = *(const float4*)&Qg[r * EE + c4];
    }
    __syncthreads();
    // ---- scores: wave owns 16 keys as register fragments, K from global/L2 ----
    {
        const float* Kg = ws + OFF_K + (size_t)(b * TT) * EE;
        int w = tid >> 6;
        int key = (tid >> 2) & 15, chunk = tid & 3;
        int coff = chunk << 5;
        for (int k0 = w << 4; k0 < nk; k0 += 64) {
            int kk = k0 + key;
            if (kk < nk) {
                float4 kf[8];
                const float4* Kr = (const float4*)&Kg[(size_t)kk * EE + coff];
                #pragma unroll
                for (int j = 0; j < 8; j++) kf[j] = Kr[j];
                #pragma unroll
                for (int q = 0; q < 8; q++) {
                    const float4* qr = (const float4*)&Qs[q][coff];
                    float s = 0.f;
                    #pragma unroll
                    for (int j = 0; j < 8; j++) {
                        float4 a = qr[j], x = kf[j];
                        s += a.x * x.x + a.y * x.y + a.z * x.z + a.w * x.w;
                    }
                    s += __shfl_xor(s, 1, 64);
                    s += __shfl_xor(s, 2, 64);
                    if (chunk == 0) S[q][kk] = s * 0.08838834764831845f;
                }
            }
        }
    }
    __syncthreads();
    // ---- softmax: 16 lanes per query ----
    if (tid < 128) {
        int q = tid >> 4, li = tid & 15;
        int tq = t0 + q;
        float sreg[16];
        float mx = -1e30f;
        #pragma unroll
        for (int m = 0; m < 16; m++) {
            int k = li + (m << 4);
            float sv = (k < nk && k <= tq) ? S[q][k] : -1e30f;
            sreg[m] = sv;
            mx = fmaxf(mx, sv);
        }
        #pragma unroll
        for (int o = 1; o < 16; o <<= 1) mx = fmaxf(mx, __shfl_xor(mx, o, 16));
        float ls = 0.f;
        #pragma unroll
        for (int m = 0; m < 16; m++) {
            float p = __expf(sreg[m] - mx);
            sreg[m] = p; ls += p;
        }
        #pragma unroll
        for (int o = 1; o < 16; o <<= 1) ls += __shfl_xor(ls, o, 16);
        float inv = 1.f / ls;
        #pragma unroll
        for (int m = 0; m < 16; m++) S[q][li + (m << 4)] = sreg[m] * inv;
    }
    __syncthreads();
    // ---- PV: threads (kc half, q, cg) 8-col float4 tiles; key-split, LDS merge ----
    {
        int kc = tid >> 7;
        int q = (tid >> 4) & 7, cg = tid & 15;
        float acc[8];
        #pragma unroll
        for (int j = 0; j < 8; j++) acc[j] = 0.f;
        const float* VPg = ws + OFF_VP + (size_t)(b * TT) * HID;
        for (int vt0 = 0; vt0 < nk; vt0 += 64) {
            __syncthreads();
            int nrow = nk - vt0; if (nrow > 64) nrow = 64;
            for (int idx = tid; idx < nrow * 25; idx += 256) {
                int r = idx / 25, c4 = (idx - r * 25) << 2;
                *(float4*)&Vs[r][c4] = *(const float4*)&VPg[(size_t)(vt0 + r) * HID + c4];
            }
            __syncthreads();
            int base = vt0 + (kc << 5);
            int kmax = nk - base; if (kmax > 32) kmax = 32;
            if (cg < 13) {
                for (int k = 0; k < kmax; k++) {
                    float p = S[q][base + k];
                    const float4* vr = (const float4*)&Vs[(kc << 5) + k][cg << 3];
                    float4 v0 = vr[0], v1 = vr[1];
                    acc[0] += p * v0.x; acc[1] += p * v0.y;
                    acc[2] += p * v0.z; acc[3] += p * v0.w;
                    acc[4] += p * v1.x; acc[5] += p * v1.y;
                    acc[6] += p * v1.z; acc[7] += p * v1.w;
                }
            }
        }
        if (kc == 1 && cg < 13) {
            float* pp = pacc[(q << 4) + cg];
            #pragma unroll
            for (int j = 0; j < 8; j++) pp[j] = acc[j];
        }
        __syncthreads();
        if (kc == 0 && cg < 13) {
            const float* pp = pacc[(q << 4) + cg];
            const float* BASEv = ws + OFF_BASE;
            const float* DP = ws + OFF_DESTPRE + b * HID;
            int c0 = cg << 3;
            #pragma unroll
            for (int j = 0; j < 8; j++) {
                int c = c0 + j;
                if (c < HID) H1P[q][c] = acc[j] + pp[j] + BASEv[c] + DP[c];
            }
        }
    }
    __syncthreads();
    // ---- phase B: stage W2s, features, h1T, GEMM, CE ----
    for (int idx = tid; idx < 5600; idx += 256) {
        int mm = idx / 56, n = idx - mm * 56;
        W2s[mm][n] = (n < H2) ? om_W2[mm * H2 + n] : 0.f;
    }
    float smean, sdinv;
    {
        float sum = ws[OFF_STATS], sq = ws[OFF_STATS + 1], cnt = ws[OFF_STATS + 2];
        smean = sum / cnt;
        float var = (sq - cnt * smean * smean) / (cnt - 1.f);
        sdinv = 1.f / (sqrtf(var) + 1e-6f);
    }
    if (tid < 64) {
        int ql = tid >> 3, d = tid & 7;
        int t = t0 + ql;
        int bt = b * TT + t;
        int v = xs[bt];
        int a = adj[v * DEG + d];
        float nbx = locations[2 * a], nby = locations[2 * a + 1];
        int dst = destinations[b];
        float dxl = locations[2 * dst], dyl = locations[2 * dst + 1];
        float cxl = locations[2 * v], cyl = locations[2 * v + 1];
        distR[tid] = (fabsf(nbx - dxl) + fabsf(nby - dyl)) * 100.f;
        float vx = nbx - cxl, vy = nby - cyl;
        float nrm = sqrtf(vx * vx + vy * vy) + 1e-8f;
        uxR[tid] = vx / nrm; uyR[tid] = vy / nrm;
        float ttn = (ws[OFF_TT + (size_t)bt * 8 + d] - smean) * sdinv;
        float obp = 0.f;
        for (int j = 0; j < 25; j++)
            obp += fmaxf(ttn * ws[OFF_V25 + j] + ws[OFF_C25 + j], 0.f) * ob_W2[j];
        obR[tid] = (a != 0) ? (obp + ob_b2[0]) : ws[OFF_OBZ];
    }
    __syncthreads();
    {
        int r = tid & 63, mq = tid >> 6;
        int qa = r >> 3;
        float dv = distR[r], ux = uxR[r], uy = uyR[r];
        const float* CD = ws + OFF_CDIST;
        const float* CX = ws + OFF_CDIRX;
        const float* CY = ws + OFF_CDIRY;
        const float* Hq = H1P[qa];
        int m0 = mq * 25;
        #pragma unroll 5
        for (int mi = 0; mi < 25; mi++) {
            int m = m0 + mi;
            float pre = Hq[m] + dv * CD[m] + ux * CX[m] + uy * CY[m];
            h1T[m][r] = fmaxf(pre, 0.f);
        }
    }
    __syncthreads();
    // ---- final GEMM: all 4 waves, 2-way m-split merged in-wave (shfl xor 8) ----
    {
        int lane = tid & 63, w = tid >> 6;
        int rg = (w << 2) | (lane >> 4);   // 0..15, 4 rows each
        int half = (lane >> 3) & 1;        // m-dimension split: 0 -> m 0..49, 1 -> m 50..99
        int cg = lane & 7;                 // 8-col group (cg==7 idle)
        int r0 = rg << 2, n0 = cg << 3;
        float facc[4][8];
        #pragma unroll
        for (int jr = 0; jr < 4; jr++)
            #pragma unroll
            for (int k = 0; k < 8; k++) facc[jr][k] = 0.f;
        if (cg < 7) {
            int m0 = half * 50;
            #pragma unroll 5
            for (int mi = 0; mi < 50; mi++) {
                int m = m0 + mi;
                float4 hv = *(const float4*)&h1T[m][r0];
                float4 w0 = *(const float4*)&W2s[m][n0];
                float4 w1 = *(const float4*)&W2s[m][n0 + 4];
                facc[0][0] += hv.x * w0.x; facc[0][1] += hv.x * w0.y; facc[0][2] += hv.x * w0.z; facc[0][3] += hv.x * w0.w;
                facc[0][4] += hv.x * w1.x; facc[0][5] += hv.x * w1.y; facc[0][6] += hv.x * w1.z; facc[0][7] += hv.x * w1.w;
                facc[1][0] += hv.y * w0.x; facc[1][1] += hv.y * w0.y; facc[1][2] += hv.y * w0.z; facc[1][3] += hv.y * w0.w;
                facc[1][4] += hv.y * w1.x; facc[1][5] += hv.y * w1.y; facc[1][6] += hv.y * w1.z; facc[1][7] += hv.y * w1.w;
                facc[2][0] += hv.z * w0.x; facc[2][1] += hv.z * w0.y; facc[2][2] += hv.z * w0.z; facc[2][3] += hv.z * w0.w;
                facc[2][4] += hv.z * w1.x; facc[2][5] += hv.z * w1.y; facc[2][6] += hv.z * w1.z; facc[2][7] += hv.z * w1.w;
                facc[3][0] += hv.w * w0.x; facc[3][1] += hv.w * w0.y; facc[3][2] += hv.w * w0.z; facc[3][3] += hv.w * w0.w;
                facc[3][4] += hv.w * w1.x; facc[3][5] += hv.w * w1.y; facc[3][6] += hv.w * w1.z; facc[3][7] += hv.w * w1.w;
            }
        }
        // merge the two m-halves (lane distance 8, same wave); ReLU must come AFTER
        #pragma unroll
        for (int jr = 0; jr < 4; jr++)
            #pragma unroll
            for (int k = 0; k < 8; k++)
                facc[jr][k] += __shfl_xor(facc[jr][k], 8, 64);
        float parts[4] = {0.f, 0.f, 0.f, 0.f};
        if (cg < 7) {
            float b2v[8], w3v[8];
            #pragma unroll
            for (int k = 0; k < 8; k++) {
                int n = n0 + k;
                b2v[k] = (n < H2) ? om_b2[n] : 0.f;
                w3v[k] = (n < H2) ? om_W3[n] : 0.f;
            }
            #pragma unroll
            for (int jr = 0; jr < 4; jr++) {
                float part = 0.f;
                #pragma unroll
                for (int k = 0; k < 8; k++)
                    part += fmaxf(facc[jr][k] + b2v[k], 0.f) * w3v[k];
                parts[jr] = part;
            }
        }
        float ob3 = om_b3[0];
        #pragma unroll
        for (int jr = 0; jr < 4; jr++) {
            float part = parts[jr];
            part += __shfl_xor(part, 1, 64);
            part += __shfl_xor(part, 2, 64);
            part += __shfl_xor(part, 4, 64);
            if ((lane & 15) == 0) lgS[r0 + jr] = part + ob3 + obR[r0 + jr];
        }
    }
    __syncthreads();
    if (tid < 8) {
        int qa = tid;
        if (qa < nqv) {
            float lg[8];
            float mxl = -1e30f;
            #pragma unroll
            for (int d = 0; d < 8; d++) {
                lg[d] = lgS[(qa << 3) + d];
                mxl = fmaxf(mxl, lg[d]);
            }
            int act = xs_actions[b * (TT - 1) + t0 + qa];
            float se = 0.f, sel = 0.f;
            #pragma unroll
            for (int d = 0; d < 8; d++) {
                se += __expf(lg[d] - mxl);
                if (d == act) sel = lg[d];
            }
            float nll = mxl + __logf(se) - sel;
            nllS[qa] = nll / (float)(len - 1);
        }
    }
    __syncthreads();
    if (tid == 0) {
        float s = 0.f;
        #pragma unroll
        for (int i = 0; i < 8; i++) s += nllS[i];
        atomicAdd(out, s);
    }
}

extern "C" void kernel_launch(void* const* d_in, const int* in_sizes, int n_in,
                              void* d_out, int out_size, void* d_ws, size_t ws_size,
                              hipStream_t stream) {
    const int* xs_padded    = (const int*)d_in[0];
    const int* lengths      = (const int*)d_in[1];
    const int* xs_actions   = (const int*)d_in[2];
    const int* destinations = (const int*)d_in[3];
    const int* adj_list     = (const int*)d_in[4];
    const int* seg_ids      = (const int*)d_in[5];
    const int* start_time   = (const int*)d_in[6];
    const float* locations  = (const float*)d_in[7];
    const float* tds        = (const float*)d_in[8];
    const float* emb        = (const float*)d_in[9];
    const float* Wq         = (const float*)d_in[10];
    const float* Wk         = (const float*)d_in[11];
    const float* Wv         = (const float*)d_in[12];
    const float* Wo         = (const float*)d_in[13];
    const float* dist_W     = (const float*)d_in[14];
    const float* dist_b     = (const float*)d_in[15];
    const float* dir_W      = (const float*)d_in[16];
    const float* dir_b      = (const float*)d_in[17];
    const float* tt_W       = (const float*)d_in[18];
    const float* tt_b       = (const float*)d_in[19];
    const float* ob_W1      = (const float*)d_in[20];
    const float* ob_b1      = (const float*)d_in[21];
    const float* ob_W2      = (const float*)d_in[22];
    const float* ob_b2      = (const float*)d_in[23];
    const float* om_W1      = (const float*)d_in[24];
    const float* om_b1      = (const float*)d_in[25];
    const float* om_W2      = (const float*)d_in[26];
    const float* om_b2      = (const float*)d_in[27];
    const float* om_W3      = (const float*)d_in[28];
    const float* om_b3      = (const float*)d_in[29];
    float* ws  = (float*)d_ws;
    float* out = (float*)d_out;

    k_setup<<<193, 256, 0, stream>>>(destinations, emb, Wo, dist_W, dist_b,
                                     dir_W, dir_b, tt_W, tt_b, ob_W1, ob_b1,
                                     ob_W2, ob_b2, om_W1, om_b1, ws, out);
    k_mid<<<768, 256, 0, stream>>>(xs_padded, lengths, adj_list, seg_ids,
                                   start_time, tds, emb, Wq, Wk, Wv, ws);
    k_attnfinal<<<BB * 32, 256, 0, stream>>>(
        lengths, xs_padded, xs_actions, destinations, adj_list, locations,
        om_W2, om_b2, om_W3, om_b3, ob_W2, ob_b2, ws, out);
}